// Round 1
// baseline (96.764 us; speedup 1.0000x reference)
//
#include <hip/hip_runtime.h>

#define NW 12
#define DIM 4096
#define NL 4
#define NG (NL*NW)              // 48 Rot gates
#define NOUT 4
#define TPB 256
#define PAIRS_PER_T (DIM/2/TPB) // 8
#define AMPS_PER_T (DIM/TPB)    // 16

// ---------------- compile-time mask machinery ----------------
// Storage psi[s] = sigma[P(s)] where P is the accumulated CNOT permutation
// (GF(2)-linear). A gate on bit p acts on storage pairs {b, b ^ P^-1(e_p)};
// the element playing the |0> role is the one with parity(b & rowmask_p)==0,
// rowmask_p[j] = bit_p(P(e_j)). All masks are input-independent -> constexpr.

struct Masks {
  unsigned pm[NG];   // pair mask  = P^-1(e_p)
  unsigned rm[NG];   // row mask   (role parity functional)
  unsigned lo[NG];   // (highest set bit of pm) - 1  (compact-index expansion)
  unsigned mr[NOUT]; // measurement row masks after all layers
};

constexpr unsigned ring_fwd(unsigned x, int r) {
  for (int w = 0; w < NW; ++w) {
    int c = NW - 1 - w, t = NW - 1 - ((w + r) % NW);
    x ^= ((x >> c) & 1u) << t;
  }
  return x;
}
constexpr unsigned ring_rev(unsigned x, int r) {
  for (int w = NW - 1; w >= 0; --w) {
    int c = NW - 1 - w, t = NW - 1 - ((w + r) % NW);
    x ^= ((x >> c) & 1u) << t;
  }
  return x;
}

constexpr Masks make_masks() {
  Masks M{};
  unsigned cols[NW] = {}, icols[NW] = {};
  for (int p = 0; p < NW; ++p) { cols[p] = 1u << p; icols[p] = 1u << p; }
  for (int l = 0; l < NL; ++l) {
    for (int w = 0; w < NW; ++w) {
      int p = NW - 1 - w;
      unsigned m = icols[p];
      M.pm[l*NW + w] = m;
      unsigned rmv = 0;
      for (int j = 0; j < NW; ++j) rmv |= ((cols[j] >> p) & 1u) << j;
      M.rm[l*NW + w] = rmv;
      unsigned h = m;
      while (h & (h - 1)) h &= h - 1;   // keep highest set bit
      M.lo[l*NW + w] = h - 1;
    }
    int rr = (l % (NW - 1)) + 1;
    // P_new = C o P : cols[j] = C(cols[j])
    for (int j = 0; j < NW; ++j) cols[j] = ring_fwd(cols[j], rr);
    // P_new^-1 = P^-1 o C^-1 : icols[p] = P^-1(C^-1(e_p))
    unsigned nic[NW] = {};
    for (int p = 0; p < NW; ++p) {
      unsigned y = ring_rev(1u << p, rr);
      unsigned v = 0;
      for (int q = 0; q < NW; ++q) if ((y >> q) & 1u) v ^= icols[q];
      nic[p] = v;
    }
    for (int p = 0; p < NW; ++p) icols[p] = nic[p];
  }
  for (int k = 0; k < NOUT; ++k) {
    int p = NW - 1 - k;
    unsigned rmv = 0;
    for (int j = 0; j < NW; ++j) rmv |= ((cols[j] >> p) & 1u) << j;
    M.mr[k] = rmv;
  }
  return M;
}

__device__ constexpr Masks MK = make_masks();

// ---------------- kernel ----------------

__global__ __launch_bounds__(TPB, 4)
void vqc_kernel(const float* __restrict__ inp,   // (B, 12)
                const float* __restrict__ wts,   // (4, 12, 3)
                float* __restrict__ out)         // (B, 4)
{
  __shared__ float2 amp[DIM];      // 32 KB state
  __shared__ float  gm[NG * 8];    // 48 gate matrices (complex 2x2)
  __shared__ float  cw[NW], sw[NW];
  __shared__ float  red[4 * NOUT]; // per-wave partials

  const int tid = threadIdx.x;
  const int b   = blockIdx.x;

  // per-sample embedding cos/sin: theta = (pi/2)*x, need cos/sin(theta/2)
  if (tid < NW) {
    float x  = inp[b * NW + tid];
    float th = 0.78539816339744830962f * x;   // pi/4 * x
    float s, c;
    sincosf(th, &s, &c);
    cw[tid] = c; sw[tid] = s;
  }
  // shared Rot matrices: Rot(phi,theta,omega) = RZ(om) RY(th) RZ(phi)
  if (tid < NG) {
    float phi = wts[tid*3 + 0], th = wts[tid*3 + 1], om = wts[tid*3 + 2];
    float st, ct;  sincosf(0.5f * th, &st, &ct);
    float ap = 0.5f * (phi + om), am = 0.5f * (phi - om);
    float sap, cap; sincosf(ap, &sap, &cap);
    float sam, cam; sincosf(am, &sam, &cam);
    float* g = &gm[tid * 8];
    g[0] =  cap * ct;  g[1] = -sap * ct;   // u00 = e^{-i ap} c
    g[2] = -cam * st;  g[3] = -sam * st;   // u01 = -e^{+i am} s
    g[4] =  cam * st;  g[5] = -sam * st;   // u10 = e^{-i am} s
    g[6] =  cap * ct;  g[7] =  sap * ct;   // u11 = e^{+i ap} c
  }
  __syncthreads();

  // product-state init (RY embedding applied to |0...0>) — all real
  #pragma unroll
  for (int j = 0; j < AMPS_PER_T; ++j) {
    unsigned idx = j * TPB + tid;
    float p = 1.0f;
    #pragma unroll
    for (int w = 0; w < NW; ++w)
      p *= ((idx >> (NW - 1 - w)) & 1u) ? sw[w] : cw[w];
    amp[idx] = make_float2(p, 0.0f);
  }

  // 48 Rot gates with lazy-permuted pair masks (CNOT rings are free)
  for (int g = 0; g < NG; ++g) {
    const unsigned m  = MK.pm[g];
    const unsigned rm = MK.rm[g];
    const unsigned lo = MK.lo[g];
    const float u00r = gm[g*8+0], u00i = gm[g*8+1];
    const float u01r = gm[g*8+2], u01i = gm[g*8+3];
    const float u10r = gm[g*8+4], u10i = gm[g*8+5];
    const float u11r = gm[g*8+6], u11i = gm[g*8+7];
    __syncthreads();
    #pragma unroll
    for (int j = 0; j < PAIRS_PER_T; ++j) {
      unsigned pi = j * TPB + tid;                       // 0..2047
      unsigned b0 = ((pi & ~lo) << 1) | (pi & lo);       // insert 0 at high bit of m
      unsigned b1 = b0 ^ m;
      bool flip = (__popc(b0 & rm) & 1);                 // conceptual-bit-p of P(b0)
      unsigned i0 = flip ? b1 : b0;
      unsigned i1 = flip ? b0 : b1;
      float2 a0 = amp[i0];
      float2 a1 = amp[i1];
      float n0r = fmaf(u00r, a0.x, fmaf(-u00i, a0.y, fmaf(u01r, a1.x, -u01i * a1.y)));
      float n0i = fmaf(u00r, a0.y, fmaf( u00i, a0.x, fmaf(u01r, a1.y,  u01i * a1.x)));
      float n1r = fmaf(u10r, a0.x, fmaf(-u10i, a0.y, fmaf(u11r, a1.x, -u11i * a1.y)));
      float n1i = fmaf(u10r, a0.y, fmaf( u10i, a0.x, fmaf(u11r, a1.y,  u11i * a1.x)));
      amp[i0] = make_float2(n0r, n0i);
      amp[i1] = make_float2(n1r, n1i);
    }
  }
  __syncthreads();

  // expval(PauliZ) on wires 0..3 — sign = parity(storage_idx & rowmask)
  float acc[NOUT] = {0.f, 0.f, 0.f, 0.f};
  #pragma unroll
  for (int j = 0; j < AMPS_PER_T; ++j) {
    unsigned idx = j * TPB + tid;
    float2 a = amp[idx];
    float pr = a.x * a.x + a.y * a.y;
    acc[0] += (__popc(idx & MK.mr[0]) & 1) ? -pr : pr;
    acc[1] += (__popc(idx & MK.mr[1]) & 1) ? -pr : pr;
    acc[2] += (__popc(idx & MK.mr[2]) & 1) ? -pr : pr;
    acc[3] += (__popc(idx & MK.mr[3]) & 1) ? -pr : pr;
  }
  #pragma unroll
  for (int k = 0; k < NOUT; ++k)
    #pragma unroll
    for (int off = 32; off > 0; off >>= 1)
      acc[k] += __shfl_down(acc[k], off);
  const int wv = tid >> 6, ln = tid & 63;
  if (ln == 0) {
    red[wv*NOUT + 0] = acc[0];
    red[wv*NOUT + 1] = acc[1];
    red[wv*NOUT + 2] = acc[2];
    red[wv*NOUT + 3] = acc[3];
  }
  __syncthreads();
  if (tid < NOUT)
    out[b * NOUT + tid] = red[0*NOUT + tid] + red[1*NOUT + tid]
                        + red[2*NOUT + tid] + red[3*NOUT + tid];
}

// ---------------- launch ----------------

extern "C" void kernel_launch(void* const* d_in, const int* in_sizes, int n_in,
                              void* d_out, int out_size, void* d_ws, size_t ws_size,
                              hipStream_t stream) {
  const float* inp = (const float*)d_in[0];   // (1024, 12) f32
  const float* wts = (const float*)d_in[1];   // (4, 12, 3) f32
  float* out = (float*)d_out;                 // (1024, 4) f32
  const int B = in_sizes[0] / NW;
  vqc_kernel<<<B, TPB, 0, stream>>>(inp, wts, out);
}

// Round 2
// 69.371 us; speedup vs baseline: 1.3949x; 1.3949x over previous
//
#include <hip/hip_runtime.h>

#define NW 12
#define DIM 4096
#define NL 4
#define NF 24                 // fused gate-pairs (2 gates each)
#define NOUT 4
#define TPB 256
#define QPT (DIM/4/TPB)       // 4 quads per thread per pass
#define APT (DIM/TPB)         // 16 amps per thread

typedef float f32x2 __attribute__((ext_vector_type(2)));
typedef float f32x4 __attribute__((ext_vector_type(4)));

// ---------------- compile-time mask machinery ----------------
// psi_storage[s] = sigma[P(s)], P = accumulated CNOT permutation (GF(2)-linear).
// Gate on conceptual bit p pairs storage {b, b ^ P^-1(e_p)}; role bit =
// parity(b & rm_p). Two gates fused -> 4x4 on quads. LDS addresses use the
// XOR swizzle phys = swz(idx) (involution, commutes with xor-masks), folded
// into all constexpr tables.

constexpr unsigned ring_fwd(unsigned x, int r) {
  for (int w = 0; w < NW; ++w) {
    int c = NW - 1 - w, t = NW - 1 - ((w + r) % NW);
    x ^= ((x >> c) & 1u) << t;
  }
  return x;
}
constexpr unsigned ring_rev(unsigned x, int r) {
  for (int w = NW - 1; w >= 0; --w) {
    int c = NW - 1 - w, t = NW - 1 - ((w + r) % NW);
    x ^= ((x >> c) & 1u) << t;
  }
  return x;
}
constexpr int hbit(unsigned x) { int h = 0; for (int i = 0; i < 16; ++i) if ((x >> i) & 1u) h = i; return h; }
constexpr unsigned swz12(unsigned x) { return x ^ ((x >> 4) & 15u) ^ ((x >> 8) & 15u); }
constexpr unsigned stT12(unsigned f) { return f ^ ((f & 15u) << 4) ^ ((f & 15u) << 8); }
constexpr unsigned compress2(unsigned v, int q1, int q2) { // remove bits q1<q2, squeeze
  unsigned lo  = v & ((1u << q1) - 1u);
  unsigned mid = (v >> (q1 + 1)) & ((1u << (q2 - q1 - 1)) - 1u);
  unsigned hi  = v >> (q2 + 1);
  return lo | (mid << q1) | (hi << (q2 - 1));
}

struct FusedTab {
  unsigned e1[NF], e2[NF];     // expansion low-masks for pivot insertion
  unsigned sm1[NF], sm2[NF];   // swizzled pair masks, byte-shifted (<<3)
  unsigned crm1[NF], crm2[NF]; // role masks compressed onto compact pi
  unsigned mrS[NOUT];          // swizzle-transposed measurement masks
};

constexpr FusedTab make_tab() {
  FusedTab T{};
  unsigned cols[NW] = {}, icols[NW] = {};
  for (int p = 0; p < NW; ++p) { cols[p] = 1u << p; icols[p] = 1u << p; }
  int fg = 0;
  for (int l = 0; l < NL; ++l) {
    for (int pr = 0; pr < 6; ++pr) {
      int p1 = NW - 1 - (2 * pr), p2 = NW - 1 - (2 * pr + 1);
      unsigned m1 = icols[p1], m2 = icols[p2];
      unsigned rm1 = 0, rm2 = 0;
      for (int j = 0; j < NW; ++j) {
        rm1 |= ((cols[j] >> p1) & 1u) << j;
        rm2 |= ((cols[j] >> p2) & 1u) << j;
      }
      int h1 = hbit(m1);
      unsigned m2r = ((m2 >> h1) & 1u) ? (m2 ^ m1) : m2;
      int h2 = hbit(m2r);
      int q1 = h1 < h2 ? h1 : h2, q2 = h1 < h2 ? h2 : h1;
      T.e1[fg] = (1u << q1) - 1u;  T.e2[fg] = (1u << q2) - 1u;
      T.sm1[fg] = swz12(m1) << 3;  T.sm2[fg] = swz12(m2) << 3;
      T.crm1[fg] = compress2(rm1, q1, q2);
      T.crm2[fg] = compress2(rm2, q1, q2);
      ++fg;
    }
    int rr = (l % (NW - 1)) + 1;
    for (int j = 0; j < NW; ++j) cols[j] = ring_fwd(cols[j], rr);
    unsigned nic[NW] = {};
    for (int p = 0; p < NW; ++p) {
      unsigned y = ring_rev(1u << p, rr);
      unsigned v = 0;
      for (int q = 0; q < NW; ++q) if ((y >> q) & 1u) v ^= icols[q];
      nic[p] = v;
    }
    for (int p = 0; p < NW; ++p) icols[p] = nic[p];
  }
  for (int k = 0; k < NOUT; ++k) {
    int p = NW - 1 - k;
    unsigned mr = 0;
    for (int j = 0; j < NW; ++j) mr |= ((cols[j] >> p) & 1u) << j;
    T.mrS[k] = stT12(mr);
  }
  return T;
}

__device__ constexpr FusedTab FT = make_tab();

// Rot(phi,theta,omega) = RZ(om) RY(th) RZ(phi), entry [r][c]
__device__ inline f32x2 rot_entry(const float* w, int r, int c) {
  float phi = w[0], th = w[1], om = w[2];
  float st, ct;  sincosf(0.5f * th, &st, &ct);
  float sap, cap; sincosf(0.5f * (phi + om), &sap, &cap);
  float sam, cam; sincosf(0.5f * (phi - om), &sam, &cam);
  f32x2 u;
  if (r == 0) { if (c == 0) { u.x =  cap * ct; u.y = -sap * ct; }
                else        { u.x = -cam * st; u.y = -sam * st; } }
  else        { if (c == 0) { u.x =  cam * st; u.y = -sam * st; }
                else        { u.x =  cap * ct; u.y =  sap * ct; } }
  return u;
}

// ---------------- kernel ----------------

__global__ __launch_bounds__(TPB, 4)
void vqc_kernel(const float* __restrict__ inp,   // (B, 12)
                const float* __restrict__ wts,   // (4, 12, 3)
                float* __restrict__ out)         // (B, 4)
{
  __shared__ f32x2 amp[DIM];        // 32 KB state (swizzled layout)
  __shared__ f32x4 fcoef[NF * 16];  // 6 KB fused 4x4 coeffs: (cr,cr,-ci,ci)
  __shared__ float cw[NW], sw[NW];
  __shared__ float red[4 * NOUT];

  const int tid = threadIdx.x;
  const int b   = blockIdx.x;

  if (tid < NW) {
    float x = inp[b * NW + tid];
    float s, c;
    sincosf(0.78539816339744830962f * x, &s, &c);  // cos/sin(theta/2), theta = pi/2*x
    cw[tid] = c; sw[tid] = s;
  }
  // fused coefficient tables (sample-independent): C[(o1,o2),(s1,s2)] = U1[o1][s1]*U2[o2][s2]
  for (int e = tid; e < NF * 16; e += TPB) {
    int fg = e >> 4, q = e & 15;
    int l = fg / 6, pr = fg % 6;
    int o1 = (q >> 3) & 1, o2 = (q >> 2) & 1, s1 = (q >> 1) & 1, s2 = q & 1;
    f32x2 u1 = rot_entry(wts + (l * NW + 2 * pr) * 3,     o1, s1);
    f32x2 u2 = rot_entry(wts + (l * NW + 2 * pr + 1) * 3, o2, s2);
    float cr = u1.x * u2.x - u1.y * u2.y;
    float ci = u1.x * u2.y + u1.y * u2.x;
    f32x4 v; v.x = cr; v.y = cr; v.z = -ci; v.w = ci;
    fcoef[e] = v;
  }
  __syncthreads();

  // product-state init (RY embedding on |0..0>), written at swizzled address
  #pragma unroll
  for (int j = 0; j < APT; ++j) {
    unsigned idx = j * TPB + tid;
    float p = 1.0f;
    #pragma unroll
    for (int w = 0; w < NW; ++w)
      p *= ((idx >> (NW - 1 - w)) & 1u) ? sw[w] : cw[w];
    unsigned ph = idx ^ ((idx >> 4) & 15u) ^ ((idx >> 8) & 15u);
    f32x2 a; a.x = p; a.y = 0.f;
    amp[ph] = a;
  }

  char* const base = (char*)amp;
  #pragma unroll 1
  for (int fg = 0; fg < NF; ++fg) {
    const unsigned e1 = FT.e1[fg], e2 = FT.e2[fg];
    const unsigned sm1 = FT.sm1[fg], sm2 = FT.sm2[fg];
    const unsigned c1 = FT.crm1[fg], c2 = FT.crm2[fg];
    f32x4 fc[16];
    #pragma unroll
    for (int c = 0; c < 16; ++c) fc[c] = fcoef[fg * 16 + c];
    __syncthreads();
    #pragma unroll
    for (int j = 0; j < QPT; ++j) {
      unsigned pi = j * TPB + tid;
      unsigned t = pi & e1;
      unsigned x = ((pi ^ t) << 1) | t;     // insert 0 at pivot q1
      t = x & e2;
      x = ((x ^ t) << 1) | t;               // insert 0 at pivot q2
      unsigned ph = x ^ ((x >> 4) & 15u) ^ ((x >> 8) & 15u);
      unsigned a00 = (ph << 3) ^ ((__popc(pi & c1) & 1) ? sm1 : 0u)
                               ^ ((__popc(pi & c2) & 1) ? sm2 : 0u);
      unsigned a01 = a00 ^ sm2, a10 = a00 ^ sm1, a11 = a10 ^ sm2;
      f32x2 v00 = *(f32x2*)(base + a00), v01 = *(f32x2*)(base + a01);
      f32x2 v10 = *(f32x2*)(base + a10), v11 = *(f32x2*)(base + a11);
      f32x2 w00 = v00.yx, w01 = v01.yx, w10 = v10.yx, w11 = v11.yx;
      f32x2 o00 = fc[ 0].xy*v00 + fc[ 0].zw*w00 + fc[ 1].xy*v01 + fc[ 1].zw*w01
                + fc[ 2].xy*v10 + fc[ 2].zw*w10 + fc[ 3].xy*v11 + fc[ 3].zw*w11;
      f32x2 o01 = fc[ 4].xy*v00 + fc[ 4].zw*w00 + fc[ 5].xy*v01 + fc[ 5].zw*w01
                + fc[ 6].xy*v10 + fc[ 6].zw*w10 + fc[ 7].xy*v11 + fc[ 7].zw*w11;
      f32x2 o10 = fc[ 8].xy*v00 + fc[ 8].zw*w00 + fc[ 9].xy*v01 + fc[ 9].zw*w01
                + fc[10].xy*v10 + fc[10].zw*w10 + fc[11].xy*v11 + fc[11].zw*w11;
      f32x2 o11 = fc[12].xy*v00 + fc[12].zw*w00 + fc[13].xy*v01 + fc[13].zw*w01
                + fc[14].xy*v10 + fc[14].zw*w10 + fc[15].xy*v11 + fc[15].zw*w11;
      *(f32x2*)(base + a00) = o00;
      *(f32x2*)(base + a01) = o01;
      *(f32x2*)(base + a10) = o10;
      *(f32x2*)(base + a11) = o11;
    }
  }
  __syncthreads();

  // expval(PauliZ) wires 0..3: sign = parity(phys & mrS)
  float acc[NOUT] = {0.f, 0.f, 0.f, 0.f};
  #pragma unroll
  for (int j = 0; j < APT; ++j) {
    unsigned i = j * TPB + tid;
    f32x2 a = amp[i];
    float pr = a.x * a.x + a.y * a.y;
    acc[0] += (__popc(i & FT.mrS[0]) & 1) ? -pr : pr;
    acc[1] += (__popc(i & FT.mrS[1]) & 1) ? -pr : pr;
    acc[2] += (__popc(i & FT.mrS[2]) & 1) ? -pr : pr;
    acc[3] += (__popc(i & FT.mrS[3]) & 1) ? -pr : pr;
  }
  #pragma unroll
  for (int k = 0; k < NOUT; ++k)
    #pragma unroll
    for (int off = 32; off > 0; off >>= 1)
      acc[k] += __shfl_down(acc[k], off);
  const int wv = tid >> 6, ln = tid & 63;
  if (ln == 0) {
    red[wv * NOUT + 0] = acc[0];
    red[wv * NOUT + 1] = acc[1];
    red[wv * NOUT + 2] = acc[2];
    red[wv * NOUT + 3] = acc[3];
  }
  __syncthreads();
  if (tid < NOUT)
    out[b * NOUT + tid] = red[0 * NOUT + tid] + red[1 * NOUT + tid]
                        + red[2 * NOUT + tid] + red[3 * NOUT + tid];
}

// ---------------- launch ----------------

extern "C" void kernel_launch(void* const* d_in, const int* in_sizes, int n_in,
                              void* d_out, int out_size, void* d_ws, size_t ws_size,
                              hipStream_t stream) {
  const float* inp = (const float*)d_in[0];   // (1024, 12) f32
  const float* wts = (const float*)d_in[1];   // (4, 12, 3) f32
  float* out = (float*)d_out;                 // (1024, 4) f32
  const int B = in_sizes[0] / NW;
  vqc_kernel<<<B, TPB, 0, stream>>>(inp, wts, out);
}

// Round 3
// 53.530 us; speedup vs baseline: 1.8076x; 1.2959x over previous
//
#include <hip/hip_runtime.h>

#define NW 12
#define DIM 4096
#define NL 4
#define NGATE 48
#define NOUT 4
#define TPB 256

typedef float f32x2 __attribute__((ext_vector_type(2)));

// ======================= constexpr GF(2) machinery =======================
// State lives in registers: phys index y = k*256 + t (k = 4 reg bits, t = tid).
// Per group g (4 gates), basis B_g: storage = B_g(phys). Constraints:
//   B_g(e_{8+i}) = m_i   (gate pair-masks -> reg bits)
//   cols(B_g) ⊥ rm_i except col 8+i  (gate role == reg bit i, no selects)
// Exchange g-1 -> g reads LDS at R(y) = Bprev^-1(B_g(y)): linear, XOR-const
// per (k, wave); planner greedily picks R's thread-bit columns with
// independent low nibbles -> conflict-floor reads.

constexpr int pcnt(unsigned x){ int c=0; for(int i=0;i<12;++i) c+=(x>>i)&1; return c; }
constexpr unsigned ring_fwd(unsigned x,int r){
  for(int w=0;w<NW;++w){ int c=NW-1-w,t=NW-1-((w+r)%NW); x^=((x>>c)&1u)<<t; } return x;
}
constexpr unsigned ring_rev(unsigned x,int r){
  for(int w=NW-1;w>=0;--w){ int c=NW-1-w,t=NW-1-((w+r)%NW); x^=((x>>c)&1u)<<t; } return x;
}

struct Mat { unsigned col[12]; };
constexpr unsigned apply_cols(const Mat&M, unsigned v){
  unsigned r=0; for(int j=0;j<12;++j) if((v>>j)&1u) r^=M.col[j]; return r;
}
constexpr unsigned apply_rows(const unsigned* rows, unsigned v){
  unsigned r=0; for(int i=0;i<12;++i) r|=(unsigned)(pcnt(rows[i]&v)&1)<<i; return r;
}
constexpr bool invert_rows(const Mat&M, unsigned* ri_out){
  unsigned rb[12], ri[12];
  for(int i=0;i<12;++i){ unsigned r=0; for(int j=0;j<12;++j) r|=((M.col[j]>>i)&1u)<<j; rb[i]=r; ri[i]=1u<<i; }
  for(int c=0;c<12;++c){
    int piv=-1; for(int r=c;r<12;++r) if((rb[r]>>c)&1u){piv=r;break;}
    if(piv<0) return false;
    unsigned t=rb[c]; rb[c]=rb[piv]; rb[piv]=t; t=ri[c]; ri[c]=ri[piv]; ri[piv]=t;
    for(int r=0;r<12;++r) if(r!=c&&((rb[r]>>c)&1u)){ rb[r]^=rb[c]; ri[r]^=ri[c]; }
  }
  for(int i=0;i<12;++i) ri_out[i]=ri[i];
  return true;
}
// null space of 4 functionals (dim must be 8)
constexpr int nullspace4(const unsigned* A0, unsigned* out){
  unsigned A[4]; for(int i=0;i<4;++i) A[i]=A0[i];
  int rank=0; int pivc[4]={-1,-1,-1,-1};
  for(int c=0;c<12&&rank<4;++c){
    int piv=-1; for(int r=rank;r<4;++r) if((A[r]>>c)&1u){piv=r;break;}
    if(piv<0) continue;
    unsigned t=A[rank];A[rank]=A[piv];A[piv]=t;
    for(int r=0;r<4;++r) if(r!=rank&&((A[r]>>c)&1u)) A[r]^=A[rank];
    pivc[rank]=c; ++rank;
  }
  if(rank!=4) return -1;
  bool ispiv[12]={};
  for(int r=0;r<4;++r) ispiv[pivc[r]]=true;
  int cnt=0;
  for(int f=0;f<12;++f) if(!ispiv[f]){
    unsigned v=1u<<f;
    for(int r=0;r<4;++r) if((A[r]>>f)&1u) v|=1u<<pivc[r];
    out[cnt++]=v;
  }
  return cnt;
}
// incremental echelon (sorted by descending lead bit)
struct Ech { unsigned r[12]; int lead[12]; int n; };
constexpr int msbp(unsigned x){ for(int i=11;i>=0;--i) if((x>>i)&1u) return i; return -1; }
constexpr unsigned ech_red(const Ech&e, unsigned v){
  int mv=msbp(v);
  for(int i=0;i<e.n&&v;++i) if(e.lead[i]==mv){ v^=e.r[i]; mv=msbp(v); }
  return v;
}
constexpr void ech_add(Ech&e, unsigned v){   // v pre-reduced, nonzero
  int l=msbp(v); int pos=e.n;
  while(pos>0&&e.lead[pos-1]<l){ e.r[pos]=e.r[pos-1]; e.lead[pos]=e.lead[pos-1]; --pos; }
  e.r[pos]=v; e.lead[pos]=l; e.n+=1;
}

struct Plan {
  unsigned SCOL0[8];      // B_0 thread-bit columns (init sigma)
  unsigned SK16_0[16];    // B_0 reg-bit XOR combos
  unsigned RCOL[12][8];   // exchange g: R columns for thread bits (g>=1)
  unsigned RK16[12][16];  // exchange g: per-k XOR offset (f32x2 units)
  unsigned SRlow[NOUT], SRhigh[NOUT];  // measurement sign masks split t/k
  bool ok;
};

constexpr Plan make_plan(){
  Plan P{}; P.ok=true;
  // ---- verified R1 lazy-CNOT mask machinery ----
  unsigned cols[12], icols[12];
  for(int p=0;p<12;++p){ cols[p]=1u<<p; icols[p]=1u<<p; }
  unsigned M[NL][12], RM[NL][12], MR[NOUT];
  for(int l=0;l<NL;++l){
    for(int w=0;w<NW;++w){
      int p=NW-1-w;
      M[l][w]=icols[p];
      unsigned r=0; for(int j=0;j<12;++j) r|=((cols[j]>>p)&1u)<<j;
      RM[l][w]=r;
    }
    int rr=(l%(NW-1))+1;
    for(int j=0;j<12;++j) cols[j]=ring_fwd(cols[j],rr);
    unsigned nic[12]={};
    for(int p=0;p<12;++p){
      unsigned y=ring_rev(1u<<p,rr), v=0;
      for(int q=0;q<12;++q) if((y>>q)&1u) v^=icols[q];
      nic[p]=v;
    }
    for(int p=0;p<12;++p) icols[p]=nic[p];
  }
  for(int o=0;o<NOUT;++o){
    int p=NW-1-o; unsigned r=0;
    for(int j=0;j<12;++j) r|=((cols[j]>>p)&1u)<<j;
    MR[o]=r;
  }
  // ---- per-group bases ----
  Mat Bprev{}; for(int j=0;j<12;++j) Bprev.col[j]=1u<<j;
  for(int g=0; g<12; ++g){
    int l=g/3, j0=(g%3)*4;
    unsigned mi[4], rmi[4];
    for(int i=0;i<4;++i){ mi[i]=M[l][j0+i]; rmi[i]=RM[l][j0+i]; }
    unsigned Wb[12];
    if(nullspace4(rmi,Wb)!=8){ P.ok=false; return P; }
    unsigned binv[12];
    if(!invert_rows(Bprev,binv)){ P.ok=false; return P; }
    unsigned Vp[8];
    for(int s=0;s<8;++s) Vp[s]=apply_rows(binv,Wb[s]);
    // greedy: 8 independent u's in span(Vp); first prefer low-nibble-independent
    unsigned u[8]={};
    Ech eu{}; Ech en{};
    for(int slot=0; slot<8; ++slot){
      unsigned pick=0; bool found=false;
      if(en.n<4){
        for(int a=0;a<8&&!found;++a){
          unsigned v=Vp[a];
          if(!ech_red(eu,v)) continue;
          if(!ech_red(en,v&15u)) continue;
          pick=v; found=true;
        }
        for(int a=0;a<8&&!found;++a) for(int b=a+1;b<8&&!found;++b){
          unsigned v=Vp[a]^Vp[b];
          if(!ech_red(eu,v)) continue;
          if(!ech_red(en,v&15u)) continue;
          pick=v; found=true;
        }
      }
      if(!found){
        for(int a=0;a<8&&!found;++a){
          unsigned v=Vp[a];
          if(ech_red(eu,v)){ pick=v; found=true; }
        }
      }
      if(!found){ P.ok=false; return P; }
      { unsigned vr=ech_red(eu,pick); ech_add(eu,vr); }
      { unsigned nr=ech_red(en,pick&15u); if(nr) ech_add(en,nr); }
      u[slot]=pick;
    }
    // build B_g
    Mat Bg{};
    for(int j=0;j<8;++j) Bg.col[j]=apply_cols(Bprev,u[j]);
    for(int i=0;i<4;++i) Bg.col[8+i]=mi[i];
    unsigned tinv[12];
    if(!invert_rows(Bg,tinv)){ P.ok=false; return P; }
    // role check: parity(col_j & rm_i) == (j==8+i)
    for(int i=0;i<4;++i)
      for(int j=0;j<12;++j){
        int want=(j==8+i)?1:0;
        if((pcnt(Bg.col[j]&rmi[i])&1)!=want){ P.ok=false; return P; }
      }
    if(g==0){
      for(int j=0;j<8;++j) P.SCOL0[j]=Bg.col[j];
      for(int k=0;k<16;++k){
        unsigned v=0; for(int i=0;i<4;++i) if((k>>i)&1) v^=Bg.col[8+i];
        P.SK16_0[k]=v;
      }
    } else {
      for(int j=0;j<8;++j) P.RCOL[g][j]=u[j];
      unsigned rk[4];
      for(int i=0;i<4;++i){
        rk[i]=apply_rows(binv,mi[i]);
        if(apply_cols(Bprev,rk[i])!=mi[i]){ P.ok=false; return P; }
      }
      for(int k=0;k<16;++k){
        unsigned v=0; for(int i=0;i<4;++i) if((k>>i)&1) v^=rk[i];
        P.RK16[g][k]=v;
      }
    }
    Bprev=Bg;
  }
  for(int o=0;o<NOUT;++o){
    unsigned sr=0;
    for(int j=0;j<12;++j) sr|=(unsigned)(pcnt(Bprev.col[j]&MR[o])&1)<<j;
    P.SRlow[o]=sr&255u; P.SRhigh[o]=sr>>8;
  }
  return P;
}

static_assert(make_plan().ok, "basis planning failed");
__device__ constexpr Plan PL = make_plan();

// ======================= kernels =======================

__device__ __forceinline__ void apply_group(f32x2* a, const float* gw_base, int g){
  #pragma unroll
  for(int i=0;i<4;++i){
    const float* w = gw_base + (g*4+i)*8;
    f32x2 c00={w[0],w[0]}, d00={-w[1],w[1]};
    f32x2 c01={w[2],w[2]}, d01={-w[3],w[3]};
    f32x2 c10={w[4],w[4]}, d10={-w[5],w[5]};
    f32x2 c11={w[6],w[6]}, d11={-w[7],w[7]};
    #pragma unroll
    for(int q=0;q<8;++q){
      const int k0=((q>>i)<<(i+1))|(q&((1<<i)-1));
      const int k1=k0|(1<<i);
      f32x2 a0=a[k0], a1=a[k1];
      f32x2 a0s=a0.yx, a1s=a1.yx;
      f32x2 n0 = c00*a0 + d00*a0s + c01*a1 + d01*a1s;
      f32x2 n1 = c10*a0 + d10*a0s + c11*a1 + d11*a1s;
      a[k0]=n0; a[k1]=n1;
    }
  }
}

__device__ __forceinline__ void gate_coeffs(const float* __restrict__ wts, int gi, float* o){
  const float* w = wts + gi*3;
  float st,ct;  sincosf(0.5f*w[1],&st,&ct);
  float sap,cap; sincosf(0.5f*(w[0]+w[2]),&sap,&cap);
  float sam,cam; sincosf(0.5f*(w[0]-w[2]),&sam,&cam);
  o[0]= cap*ct; o[1]=-sap*ct;
  o[2]=-cam*st; o[3]=-sam*st;
  o[4]= cam*st; o[5]=-sam*st;
  o[6]= cap*ct; o[7]= sap*ct;
}

__global__ void coeff_kernel(const float* __restrict__ wts, float* __restrict__ gws){
  int gi = threadIdx.x;
  if(gi >= NGATE) return;
  float o[8];
  gate_coeffs(wts, gi, o);
  #pragma unroll
  for(int j=0;j<8;++j) gws[gi*8+j]=o[j];
}

template<bool USE_WS>
__global__ __launch_bounds__(TPB,4)
void vqc_kernel(const float* __restrict__ inp,   // (B,12)
                const float* __restrict__ wts,   // (4,12,3) (fallback path)
                const float* __restrict__ gws,   // (48,8) precomputed coeffs
                float* __restrict__ out)         // (B,4)
{
  __shared__ f32x2 amp[DIM];                      // 32 KB exchange buffer
  __shared__ float cs[NW], ss[NW];
  __shared__ float red[4*NOUT];
  __shared__ float gtab[USE_WS?1:NGATE*8];

  const int t = threadIdx.x;
  const int b = blockIdx.x;

  if(t < NW){
    float x = inp[b*NW+t];
    float s,c; sincosf(0.78539816339744830962f*x,&s,&c);
    cs[t]=c; ss[t]=s;
  }
  if(!USE_WS && t < NGATE){
    float o[8]; gate_coeffs(wts,t,o);
    #pragma unroll
    for(int j=0;j<8;++j) gtab[t*8+j]=o[j];
  }
  __syncthreads();

  const float* gw = USE_WS ? gws : (const float*)gtab;

  float cr[NW], sr_[NW];
  #pragma unroll
  for(int w=0;w<NW;++w){ cr[w]=cs[w]; sr_[w]=ss[w]; }

  // product-state init directly in basis B_0
  unsigned sig_t=0;
  #pragma unroll
  for(int j=0;j<8;++j) sig_t ^= ((t>>j)&1u)? PL.SCOL0[j] : 0u;
  f32x2 a[16];
  #pragma unroll
  for(int k=0;k<16;++k){
    unsigned sig = sig_t ^ PL.SK16_0[k];
    float p=1.f;
    #pragma unroll
    for(int w=0;w<NW;++w) p *= ((sig>>(NW-1-w))&1u)? sr_[w] : cr[w];
    a[k].x=p; a[k].y=0.f;
  }

  apply_group(a, gw, 0);

  #pragma unroll 1
  for(int g=1; g<12; ++g){
    __syncthreads();                       // prior reads done before overwrite
    #pragma unroll
    for(int k=0;k<16;++k) amp[k*256+t]=a[k];   // linear write: conflict-free
    __syncthreads();
    unsigned base=0;
    #pragma unroll
    for(int j=0;j<8;++j) base ^= ((t>>j)&1u)? PL.RCOL[g][j] : 0u;
    #pragma unroll
    for(int k=0;k<16;++k) a[k]=amp[base ^ PL.RK16[g][k]];
    apply_group(a, gw, g);
  }

  // expval(PauliZ) on wires 0..3 from registers
  float acc[NOUT]={0.f,0.f,0.f,0.f};
  float sg[NOUT];
  #pragma unroll
  for(int o=0;o<NOUT;++o)
    sg[o] = (__popc((unsigned)t & PL.SRlow[o])&1)? -1.f : 1.f;
  #pragma unroll
  for(int k=0;k<16;++k){
    float pr = a[k].x*a[k].x + a[k].y*a[k].y;
    #pragma unroll
    for(int o=0;o<NOUT;++o){
      const bool kp = (pcnt((unsigned)k & PL.SRhigh[o])&1)!=0;  // compile-time
      float f = sg[o]*pr;
      acc[o] += kp ? -f : f;
    }
  }
  #pragma unroll
  for(int o=0;o<NOUT;++o)
    #pragma unroll
    for(int off=32; off>0; off>>=1)
      acc[o] += __shfl_down(acc[o], off);
  const int wv=t>>6, ln=t&63;
  if(ln==0){
    #pragma unroll
    for(int o=0;o<NOUT;++o) red[wv*NOUT+o]=acc[o];
  }
  __syncthreads();
  if(t<NOUT)
    out[b*NOUT+t] = red[0*NOUT+t]+red[1*NOUT+t]+red[2*NOUT+t]+red[3*NOUT+t];
}

// ======================= launch =======================

extern "C" void kernel_launch(void* const* d_in, const int* in_sizes, int n_in,
                              void* d_out, int out_size, void* d_ws, size_t ws_size,
                              hipStream_t stream) {
  const float* inp=(const float*)d_in[0];   // (1024,12) f32
  const float* wts=(const float*)d_in[1];   // (4,12,3) f32
  float* outp=(float*)d_out;                // (1024,4) f32
  const int B = in_sizes[0]/NW;
  if(ws_size >= (size_t)(NGATE*8*sizeof(float))){
    float* gws=(float*)d_ws;
    coeff_kernel<<<1,64,0,stream>>>(wts,gws);
    vqc_kernel<true><<<B,TPB,0,stream>>>(inp,wts,gws,outp);
  } else {
    vqc_kernel<false><<<B,TPB,0,stream>>>(inp,wts,nullptr,outp);
  }
}